// Round 4
// baseline (68.171 us; speedup 1.0000x reference)
//
#include <hip/hip_runtime.h>

// LearnableDCT: x (32,3,512,512) f32, basis (64,64) f32
// out (32, 192, 64, 64) f32 : out[b][c*64+k][hb][wb] = sum_n basis[k][n] * block[n]
// block[n=i*8+j] = x[b][c][hb*8+i][wb*8+j]
//
// Round-3 post-mortem: VGPR_Count=76 < the 128 live floats the 2-block
// version needed -> compiler reloaded ~50 floats/iter through L1/L2
// (~2.5 GB at L2 BW ~= the whole 78us duration). Fix: one block per
// thread (64 live floats) held in 16 NAMED float4 SSA values (no alloca,
// nothing to demote), clean pointer-bump addressing, scalar basis stream.

#define ROW_LOAD(i) \
    const float4 qa##i = *reinterpret_cast<const float4*>(xp + (i) * 512); \
    const float4 qb##i = *reinterpret_cast<const float4*>(xp + (i) * 512 + 4);

#define ROW_FMA(i) \
    a0 = fmaf(bk[(i)*8+0], qa##i.x, a0); \
    a1 = fmaf(bk[(i)*8+1], qa##i.y, a1); \
    a2 = fmaf(bk[(i)*8+2], qa##i.z, a2); \
    a3 = fmaf(bk[(i)*8+3], qa##i.w, a3); \
    a0 = fmaf(bk[(i)*8+4], qb##i.x, a0); \
    a1 = fmaf(bk[(i)*8+5], qb##i.y, a1); \
    a2 = fmaf(bk[(i)*8+6], qb##i.z, a2); \
    a3 = fmaf(bk[(i)*8+7], qb##i.w, a3);

__global__ __launch_bounds__(256) void dct_kernel(
    const float* __restrict__ x,
    const float* __restrict__ basis,
    float* __restrict__ out)
{
    const int tid    = blockIdx.x * 256 + threadIdx.x;
    const int within = tid & 4095;   // hb*64 + wb
    const int bc     = tid >> 12;    // 0..95
    const int wb     = within & 63;  // lane == wb: coalesced loads + stores
    const int hb     = within >> 6;

    // x base: bc*512*512 + (hb*8)*512 + wb*8
    const float* xp = x + ((size_t)bc << 18) + ((size_t)hb << 12) + (wb << 3);

    // 8x8 block in 16 named float4 registers (64 VGPRs, guaranteed SSA)
    ROW_LOAD(0) ROW_LOAD(1) ROW_LOAD(2) ROW_LOAD(3)
    ROW_LOAD(4) ROW_LOAD(5) ROW_LOAD(6) ROW_LOAD(7)

    // out base: (bc*64 + k)*4096 + within ; k step = 4096 floats
    float* op = out + ((size_t)bc << 18) + within;

    const float* bk = basis;   // wave-uniform -> s_load stream
    #pragma unroll 1
    for (int k = 0; k < 64; ++k) {
        float a0 = 0.f, a1 = 0.f, a2 = 0.f, a3 = 0.f;
        ROW_FMA(0) ROW_FMA(1) ROW_FMA(2) ROW_FMA(3)
        ROW_FMA(4) ROW_FMA(5) ROW_FMA(6) ROW_FMA(7)
        __builtin_nontemporal_store((a0 + a1) + (a2 + a3), op);
        bk += 64;
        op += 4096;
    }
}

extern "C" void kernel_launch(void* const* d_in, const int* in_sizes, int n_in,
                              void* d_out, int out_size, void* d_ws, size_t ws_size,
                              hipStream_t stream) {
    const float* x     = (const float*)d_in[0];
    const float* basis = (const float*)d_in[1];
    float* out         = (float*)d_out;

    // threads = 32*3*64*64 = 393216 -> 1536 WGs of 256
    dct_kernel<<<dim3(1536), dim3(256), 0, stream>>>(x, basis, out);
}

// Round 5
// 67.244 us; speedup vs baseline: 1.0138x; 1.0138x over previous
//
#include <hip/hip_runtime.h>

// LearnableDCT: x (32,3,512,512) f32, basis (64,64) f32
// out (32, 192, 64, 64) f32 : out[b][c*64+k][hb][wb] = sum_n basis[k][n] * block[n]
// block[n=i*8+j] = x[b][c][hb*8+i][wb*8+j]
//
// Round-4 post-mortem: VGPR_Count=44 — hipcc REMATERIALIZED the loop-invariant
// x loads inside the k-loop (chasing occupancy), re-reading the block from
// L1/L2 64 times. Named float4 SSA wasn't enough: any pure-load value can be
// re-derived. Fix: pin each of the 64 block values with asm volatile
// ("+v") — the asm nominally modifies the value, so remat is illegal and the
// block MUST stay in VGPRs across the whole k-loop.

__global__ __launch_bounds__(256, 2) void dct_kernel(
    const float* __restrict__ x,
    const float* __restrict__ basis,
    float* __restrict__ out)
{
    const int tid    = blockIdx.x * 256 + threadIdx.x;
    const int within = tid & 4095;   // hb*64 + wb
    const int bc     = tid >> 12;    // 0..95
    const int wb     = within & 63;  // lane == wb: coalesced loads + stores
    const int hb     = within >> 6;

    // x base: bc*512*512 + (hb*8)*512 + wb*8
    const float* xp = x + ((size_t)bc << 18) + ((size_t)hb << 12) + (wb << 3);

    // 8x8 block -> 64 named scalars
    float xr[64];
    #pragma unroll
    for (int i = 0; i < 8; ++i) {
        float4 a = *reinterpret_cast<const float4*>(xp + i * 512);
        float4 b = *reinterpret_cast<const float4*>(xp + i * 512 + 4);
        xr[i*8+0]=a.x; xr[i*8+1]=a.y; xr[i*8+2]=a.z; xr[i*8+3]=a.w;
        xr[i*8+4]=b.x; xr[i*8+5]=b.y; xr[i*8+6]=b.z; xr[i*8+7]=b.w;
    }
    // Pin every element in a VGPR: compiler cannot rematerialize past this.
    #pragma unroll
    for (int n = 0; n < 64; ++n) {
        asm volatile("" : "+v"(xr[n]));
    }

    // out base: (bc*64 + k)*4096 + within ; k step = 4096 floats
    float* op = out + ((size_t)bc << 18) + within;

    const float* bk = basis;   // wave-uniform -> s_load stream
    #pragma unroll 1
    for (int k = 0; k < 64; ++k) {
        float a0 = 0.f, a1 = 0.f, a2 = 0.f, a3 = 0.f;
        #pragma unroll
        for (int n = 0; n < 64; n += 4) {
            a0 = fmaf(bk[n + 0], xr[n + 0], a0);
            a1 = fmaf(bk[n + 1], xr[n + 1], a1);
            a2 = fmaf(bk[n + 2], xr[n + 2], a2);
            a3 = fmaf(bk[n + 3], xr[n + 3], a3);
        }
        __builtin_nontemporal_store((a0 + a1) + (a2 + a3), op);
        bk += 64;
        op += 4096;
    }
}

extern "C" void kernel_launch(void* const* d_in, const int* in_sizes, int n_in,
                              void* d_out, int out_size, void* d_ws, size_t ws_size,
                              hipStream_t stream) {
    const float* x     = (const float*)d_in[0];
    const float* basis = (const float*)d_in[1];
    float* out         = (float*)d_out;

    // threads = 32*3*64*64 = 393216 -> 1536 WGs of 256
    dct_kernel<<<dim3(1536), dim3(256), 0, stream>>>(x, basis, out);
}

// Round 6
// 54.070 us; speedup vs baseline: 1.2608x; 1.2436x over previous
//
#include <hip/hip_runtime.h>

// LearnableDCT: x (32,3,512,512) f32, basis (64,64) f32
// out (32, 192, 64, 64) f32 : out[b][c*64+k][hb][wb] = sum_n basis[k][n] * block[n]
// block[n=i*8+j] = x[b][c][hb*8+i][wb*8+j]
//
// Rounds 4/5 post-mortem: any structure holding the x-block live across the
// k-loop loses to regalloc (remat or scratch spill; VGPR_Count=44 both times).
// Fix: LOOP INTERCHANGE. Keep acc[64] (one per output k) live instead —
// accumulators are loop-carried RMW values the spill-cost model protects —
// and stream x through transient regs that die immediately. Requires basis^T
// (contiguous column-n reads for the scalar path), produced by a tiny
// pre-kernel into d_ws.

__global__ void transpose_basis(const float* __restrict__ b,
                                float* __restrict__ bt)
{
    // 64x64: bt[n][k] = b[k][n]; one WG of 256, 16 elems/thread
    const int t = threadIdx.x;
    #pragma unroll
    for (int r = 0; r < 16; ++r) {
        const int idx = t + r * 256;      // 0..4095
        const int n = idx >> 6, k = idx & 63;
        bt[n * 64 + k] = b[k * 64 + n];
    }
}

__global__ __launch_bounds__(256) void dct_kernel(
    const float* __restrict__ x,
    const float* __restrict__ bt,    // basis^T, (n,k)
    float* __restrict__ out)
{
    const int tid    = blockIdx.x * 256 + threadIdx.x;
    const int within = tid & 4095;   // hb*64 + wb
    const int bc     = tid >> 12;    // 0..95
    const int wb     = within & 63;  // lane == wb: coalesced loads + stores
    const int hb     = within >> 6;

    // x base: bc*512*512 + (hb*8)*512 + wb*8
    const float* xp = x + ((size_t)bc << 18) + ((size_t)hb << 12) + (wb << 3);

    float acc[64];
    #pragma unroll
    for (int k = 0; k < 64; ++k) acc[k] = 0.f;

    #pragma unroll 1
    for (int i = 0; i < 8; ++i) {
        const float4 a = *reinterpret_cast<const float4*>(xp + i * 512);
        const float4 b = *reinterpret_cast<const float4*>(xp + i * 512 + 4);
        const float xv[8] = {a.x, a.y, a.z, a.w, b.x, b.y, b.z, b.w};
        const float* bn = bt + (i << 9);      // row n=i*8 of basis^T, uniform
        #pragma unroll
        for (int j = 0; j < 8; ++j) {
            const float xn = xv[j];           // transient: dies after 64 fmas
            #pragma unroll
            for (int k = 0; k < 64; ++k)
                acc[k] = fmaf(bn[j * 64 + k], xn, acc[k]);
        }
    }

    // out base: (bc*64 + k)*4096 + within ; k step = 4096 floats
    float* op = out + ((size_t)bc << 18) + within;
    #pragma unroll
    for (int k = 0; k < 64; ++k)
        __builtin_nontemporal_store(acc[k], op + ((size_t)k << 12));
}

extern "C" void kernel_launch(void* const* d_in, const int* in_sizes, int n_in,
                              void* d_out, int out_size, void* d_ws, size_t ws_size,
                              hipStream_t stream) {
    const float* x     = (const float*)d_in[0];
    const float* basis = (const float*)d_in[1];
    float* out         = (float*)d_out;
    float* bt          = (float*)d_ws;   // 16 KB

    transpose_basis<<<dim3(1), dim3(256), 0, stream>>>(basis, bt);
    // threads = 32*3*64*64 = 393216 -> 1536 WGs of 256
    dct_kernel<<<dim3(1536), dim3(256), 0, stream>>>(x, bt, out);
}

// Round 7
// 52.553 us; speedup vs baseline: 1.2972x; 1.0289x over previous
//
#include <hip/hip_runtime.h>

// LearnableDCT: x (32,3,512,512) f32, basis (64,64) f32
// out (32, 192, 64, 64) f32 : out[b][c*64+k][hb][wb] = sum_n basis[k][n] * block[n]
// block[n=i*8+j] = x[b][c][hb*8+i][wb*8+j]
//
// Round-6 post-mortem: compiler insists on ~16 live accumulators (VGPR=40,
// self-fissioned), and grid of 6144 waves < 8192-wave device capacity left
// 59% of time as unhidden latency (VALUBusy 41%, occupancy 50%). Round 7:
// embrace 16 accs/thread — split k into quarters BY WAVE (k0 wave-uniform,
// readfirstlane-pinned to SGPR so basis^T stays a scalar s_load stream),
// 4 waves of a WG share one 64-block set (x re-reads are L1/L2 hits, and x
// is L3-resident anyway: steady-state FETCH ~= 0). Grid: 6144 WGs = 24576
// waves = 3x capacity -> latency fully hidden.

__global__ void transpose_basis(const float* __restrict__ b,
                                float* __restrict__ bt)
{
    // 64x64: bt[n][k] = b[k][n]; one WG of 256, 16 elems/thread
    const int t = threadIdx.x;
    #pragma unroll
    for (int r = 0; r < 16; ++r) {
        const int idx = t + r * 256;      // 0..4095
        const int n = idx >> 6, k = idx & 63;
        bt[n * 64 + k] = b[k * 64 + n];
    }
}

__global__ __launch_bounds__(256, 8) void dct_kernel(
    const float* __restrict__ x,
    const float* __restrict__ bt,    // basis^T, (n,k)
    float* __restrict__ out)
{
    // WG g covers blocks [g*64, g*64+64): bc = g>>6, hb = g&63, wb = lane.
    const int g  = blockIdx.x;
    const int wb = threadIdx.x & 63;
    const int hb = g & 63;
    const int bc = g >> 6;
    // wave-uniform k-quarter, pinned to SGPR
    const int k0 = __builtin_amdgcn_readfirstlane((threadIdx.x >> 6) << 4);

    // x base: bc*512*512 + (hb*8)*512 + wb*8
    const float* xp = x + ((size_t)bc << 18) + ((size_t)hb << 12) + (wb << 3);

    float acc[16];
    #pragma unroll
    for (int k = 0; k < 16; ++k) acc[k] = 0.f;

    #pragma unroll 1
    for (int i = 0; i < 8; ++i) {
        const float4 a = *reinterpret_cast<const float4*>(xp + i * 512);
        const float4 b = *reinterpret_cast<const float4*>(xp + i * 512 + 4);
        const float xv[8] = {a.x, a.y, a.z, a.w, b.x, b.y, b.z, b.w};
        const float* bn = bt + (i << 9) + k0;   // uniform -> s_load_dwordx16
        #pragma unroll
        for (int j = 0; j < 8; ++j) {
            const float xn = xv[j];             // transient
            #pragma unroll
            for (int k = 0; k < 16; ++k)
                acc[k] = fmaf(bn[j * 64 + k], xn, acc[k]);
        }
    }

    // out base: (bc*64 + k0 + k)*4096 + hb*64 + wb
    float* op = out + ((size_t)bc << 18) + ((size_t)k0 << 12) + (hb << 6) + wb;
    #pragma unroll
    for (int k = 0; k < 16; ++k)
        __builtin_nontemporal_store(acc[k], op + ((size_t)k << 12));
}

extern "C" void kernel_launch(void* const* d_in, const int* in_sizes, int n_in,
                              void* d_out, int out_size, void* d_ws, size_t ws_size,
                              hipStream_t stream) {
    const float* x     = (const float*)d_in[0];
    const float* basis = (const float*)d_in[1];
    float* out         = (float*)d_out;
    float* bt          = (float*)d_ws;   // 16 KB

    transpose_basis<<<dim3(1), dim3(256), 0, stream>>>(basis, bt);
    // 393216 blocks / 64 per WG = 6144 WGs (24576 waves)
    dct_kernel<<<dim3(6144), dim3(256), 0, stream>>>(x, bt, out);
}

// Round 8
// 46.004 us; speedup vs baseline: 1.4818x; 1.1423x over previous
//
#include <hip/hip_runtime.h>

// LearnableDCT as a GEMM on matrix cores.
// out[bc*64+k][hb*64+wb] = sum_n basis[k][n] * x[bc][hb*8+i][wb*8+j], n=i*8+j
// = C(64k x 393216 blocks) = basis(64x64) * X(64 x 393216)  ->  MFMA.
//
// Round-7 post-mortem: VALU issue alone was 33us (fp32 FMA floor 20.5us, no
// fp32 MFMA) while steady-state HBM traffic is writes-only 98MB (~16us floor).
// MFMA cuts the FLOP issue 8x -> write-BW-bound kernel.
//
// Precision: hi/lo bf16 split of BOTH operands (bh*xh + bh*xl + bl*xh);
// residual error ~2^-18 relative = fp32-grade, 3 MFMAs per pair (still ~nothing).
//
// Fragments (mfma_f32_16x16x32_bf16, m89/m92-verified mappings):
//   A(basis): lane l, elem j -> row k=16t+(l&15), n = 8*(l>>4) + 32h + j
//   B(x):     lane l, elem j -> col block wb0+(l&15), same n mapping
//   D:        lane l, reg r  -> row k=16t+(l>>4)*4+r, col block wb0+(l&15)
// B's 8 elems = 8 contiguous floats of one x row -> 2x float4, no LDS.

typedef float f32x4 __attribute__((ext_vector_type(4)));
typedef __bf16 bf16x8 __attribute__((ext_vector_type(8)));

static __device__ __forceinline__ f32x4 mfma16(bf16x8 a, bf16x8 b, f32x4 c) {
    return __builtin_amdgcn_mfma_f32_16x16x32_bf16(a, b, c, 0, 0, 0);
}

// Pre-kernel: basis -> per-lane hi/lo A-fragments in ws.
// ws layout: [F=((t*2+h)*2+p)][lane][8 bf16], 16 frags * 1KB = 16KB.
__global__ void basis_frags(const float* __restrict__ bsrc,
                            __bf16* __restrict__ ws)
{
    const int lane = threadIdx.x & 63;
    #pragma unroll
    for (int rr = 0; rr < 2; ++rr) {
        const int th = (threadIdx.x >> 6) + rr * 4;   // 0..7 : t=th>>1, h=th&1
        const int kk = ((th >> 1) << 4) + (lane & 15);
        const int nn = ((lane >> 4) << 3) + ((th & 1) << 5);
        const int Fh = th * 2, Fl = th * 2 + 1;
        #pragma unroll
        for (int j = 0; j < 8; ++j) {
            const float v = bsrc[kk * 64 + nn + j];
            const __bf16 h = (__bf16)v;
            ws[(Fh * 64 + lane) * 8 + j] = h;
            ws[(Fl * 64 + lane) * 8 + j] = (__bf16)(v - (float)h);
        }
    }
}

#define MAKE_BX(va, vb, XH, XL)                                        \
    {                                                                  \
        const float vv[8] = {va.x, va.y, va.z, va.w,                   \
                             vb.x, vb.y, vb.z, vb.w};                  \
        _Pragma("unroll")                                              \
        for (int j = 0; j < 8; ++j) {                                  \
            const __bf16 hh = (__bf16)vv[j];                           \
            XH[j] = hh;                                                \
            XL[j] = (__bf16)(vv[j] - (float)hh);                       \
        }                                                              \
    }

__global__ __launch_bounds__(256) void dct_mfma(
    const float* __restrict__ x,
    const __bf16* __restrict__ wsf,
    float* __restrict__ out)
{
    const int lane = threadIdx.x & 63;
    const int wv   = threadIdx.x >> 6;   // 0..3
    const int g    = blockIdx.x;
    const int hb   = g & 63;
    const int bc   = g >> 6;
    const int c15  = lane & 15;
    const int gq   = lane >> 4;          // 0..3
    const int wb0  = wv << 4;

    // A fragments (L1/L2-resident 16KB, same for every wave)
    bf16x8 A[16];
    const uint4* wp = reinterpret_cast<const uint4*>(wsf) + lane;
    #pragma unroll
    for (int F = 0; F < 16; ++F)
        A[F] = __builtin_bit_cast(bf16x8, wp[F * 64]);

    // B fragments: rows i=gq (n-half 0) and i=gq+4 (n-half 1)
    const float* xp = x + ((size_t)bc << 18) + ((size_t)hb << 12)
                        + ((wb0 + c15) << 3);
    const float4 a0 = *reinterpret_cast<const float4*>(xp + gq * 512);
    const float4 a1 = *reinterpret_cast<const float4*>(xp + gq * 512 + 4);
    const float4 b0 = *reinterpret_cast<const float4*>(xp + (gq + 4) * 512);
    const float4 b1 = *reinterpret_cast<const float4*>(xp + (gq + 4) * 512 + 4);

    bf16x8 Xh0, Xl0, Xh1, Xl1;
    MAKE_BX(a0, a1, Xh0, Xl0)
    MAKE_BX(b0, b1, Xh1, Xl1)

    float* ob = out + ((size_t)bc << 18) + (hb << 6) + wb0 + c15;

    #pragma unroll
    for (int t = 0; t < 4; ++t) {
        f32x4 c = {0.f, 0.f, 0.f, 0.f};
        // h = 0
        c = mfma16(A[(t*2+0)*2+0], Xh0, c);   // bh*xh
        c = mfma16(A[(t*2+0)*2+0], Xl0, c);   // bh*xl
        c = mfma16(A[(t*2+0)*2+1], Xh0, c);   // bl*xh
        // h = 1
        c = mfma16(A[(t*2+1)*2+0], Xh1, c);
        c = mfma16(A[(t*2+1)*2+0], Xl1, c);
        c = mfma16(A[(t*2+1)*2+1], Xh1, c);

        float* op = ob + ((size_t)((t << 4) + (gq << 2)) << 12);
        #pragma unroll
        for (int r = 0; r < 4; ++r)
            __builtin_nontemporal_store(c[r], op + ((size_t)r << 12));
    }
}

extern "C" void kernel_launch(void* const* d_in, const int* in_sizes, int n_in,
                              void* d_out, int out_size, void* d_ws, size_t ws_size,
                              hipStream_t stream) {
    const float* x     = (const float*)d_in[0];
    const float* basis = (const float*)d_in[1];
    float* out         = (float*)d_out;
    __bf16* ws         = (__bf16*)d_ws;    // 16 KB

    basis_frags<<<dim3(1), dim3(256), 0, stream>>>(basis, ws);
    // 96 bc * 64 hb = 6144 WGs; wave wv covers wb in [16wv,16wv+16)
    dct_mfma<<<dim3(6144), dim3(256), 0, stream>>>(x, ws, out);
}

// Round 9
// 41.292 us; speedup vs baseline: 1.6510x; 1.1141x over previous
//
#include <hip/hip_runtime.h>

// LearnableDCT as GEMM on matrix cores (16x16x32 bf16, hi/lo split for fp32
// accuracy) + LDS-transposed epilogue for full-line coalesced stores.
//
// Round-8 post-mortem: datapath fine, but D-fragment stores (64B per 16-lane
// group = half an L2 line) caused 27% HBM write amplification
// (WRITE_SIZE 98.3 -> 124.7 MB) and store-path stalls. Fix: stage the WG's
// 64k x 64wb tile in LDS (stride 68: both write and read patterns are 2
// lanes/bank = conflict-free), then store each k-row as 64 contiguous dwords
// (256B, full 128B lines) exactly like rounds 6/7 which wrote 98.3MB clean.

typedef float f32x4 __attribute__((ext_vector_type(4)));
typedef __bf16 bf16x8 __attribute__((ext_vector_type(8)));

static __device__ __forceinline__ f32x4 mfma16(bf16x8 a, bf16x8 b, f32x4 c) {
    return __builtin_amdgcn_mfma_f32_16x16x32_bf16(a, b, c, 0, 0, 0);
}

// Pre-kernel: basis -> per-lane hi/lo A-fragments in ws (verified round 8).
// ws layout: [F=((t*2+h)*2+p)][lane][8 bf16], 16 frags * 1KB = 16KB.
__global__ void basis_frags(const float* __restrict__ bsrc,
                            __bf16* __restrict__ ws)
{
    const int lane = threadIdx.x & 63;
    #pragma unroll
    for (int rr = 0; rr < 2; ++rr) {
        const int th = (threadIdx.x >> 6) + rr * 4;   // 0..7 : t=th>>1, h=th&1
        const int kk = ((th >> 1) << 4) + (lane & 15);
        const int nn = ((lane >> 4) << 3) + ((th & 1) << 5);
        const int Fh = th * 2, Fl = th * 2 + 1;
        #pragma unroll
        for (int j = 0; j < 8; ++j) {
            const float v = bsrc[kk * 64 + nn + j];
            const __bf16 h = (__bf16)v;
            ws[(Fh * 64 + lane) * 8 + j] = h;
            ws[(Fl * 64 + lane) * 8 + j] = (__bf16)(v - (float)h);
        }
    }
}

#define MAKE_BX(va, vb, XH, XL)                                        \
    {                                                                  \
        const float vv[8] = {va.x, va.y, va.z, va.w,                   \
                             vb.x, vb.y, vb.z, vb.w};                  \
        _Pragma("unroll")                                              \
        for (int j = 0; j < 8; ++j) {                                  \
            const __bf16 hh = (__bf16)vv[j];                           \
            XH[j] = hh;                                                \
            XL[j] = (__bf16)(vv[j] - (float)hh);                       \
        }                                                              \
    }

#define LSTRIDE 68   // dword stride: 4k%32 bank rotation -> 2-way (free) both phases

__global__ __launch_bounds__(256) void dct_mfma(
    const float* __restrict__ x,
    const __bf16* __restrict__ wsf,
    float* __restrict__ out)
{
    __shared__ float lds[64 * LSTRIDE];   // 17.4 KB

    const int lane = threadIdx.x & 63;
    const int wv   = threadIdx.x >> 6;   // 0..3
    const int g    = blockIdx.x;
    const int hb   = g & 63;
    const int bc   = g >> 6;
    const int c15  = lane & 15;
    const int gq   = lane >> 4;          // 0..3
    const int wb0  = wv << 4;

    // A fragments (L1/L2-resident 16KB, same for every wave)
    bf16x8 A[16];
    const uint4* wp = reinterpret_cast<const uint4*>(wsf) + lane;
    #pragma unroll
    for (int F = 0; F < 16; ++F)
        A[F] = __builtin_bit_cast(bf16x8, wp[F * 64]);

    // B fragments: rows i=gq (n-half 0) and i=gq+4 (n-half 1) of block wb0+c15
    const float* xp = x + ((size_t)bc << 18) + ((size_t)hb << 12)
                        + ((wb0 + c15) << 3);
    const float4 a0 = *reinterpret_cast<const float4*>(xp + gq * 512);
    const float4 a1 = *reinterpret_cast<const float4*>(xp + gq * 512 + 4);
    const float4 b0 = *reinterpret_cast<const float4*>(xp + (gq + 4) * 512);
    const float4 b1 = *reinterpret_cast<const float4*>(xp + (gq + 4) * 512 + 4);

    bf16x8 Xh0, Xl0, Xh1, Xl1;
    MAKE_BX(a0, a1, Xh0, Xl0)
    MAKE_BX(b0, b1, Xh1, Xl1)

    #pragma unroll
    for (int t = 0; t < 4; ++t) {
        f32x4 c = {0.f, 0.f, 0.f, 0.f};
        c = mfma16(A[(t*2+0)*2+0], Xh0, c);   // bh*xh
        c = mfma16(A[(t*2+0)*2+0], Xl0, c);   // bh*xl
        c = mfma16(A[(t*2+0)*2+1], Xh0, c);   // bl*xh
        c = mfma16(A[(t*2+1)*2+0], Xh1, c);
        c = mfma16(A[(t*2+1)*2+0], Xl1, c);
        c = mfma16(A[(t*2+1)*2+1], Xh1, c);

        const int kbase = (t << 4) + (gq << 2);   // row k = kbase + r
        #pragma unroll
        for (int r = 0; r < 4; ++r)
            lds[(kbase + r) * LSTRIDE + wb0 + c15] = c[r];
    }

    __syncthreads();

    // Epilogue: wave wv stores rows k in [16wv, 16wv+16); lane = wb.
    // Each store: 64 lanes x 4B contiguous = 256B full lines.
    float* ob = out + ((size_t)bc << 18) + (hb << 6) + lane;
    #pragma unroll
    for (int kk = 0; kk < 16; ++kk) {
        const int k = (wv << 4) + kk;
        __builtin_nontemporal_store(lds[k * LSTRIDE + lane],
                                    ob + ((size_t)k << 12));
    }
}

extern "C" void kernel_launch(void* const* d_in, const int* in_sizes, int n_in,
                              void* d_out, int out_size, void* d_ws, size_t ws_size,
                              hipStream_t stream) {
    const float* x     = (const float*)d_in[0];
    const float* basis = (const float*)d_in[1];
    float* out         = (float*)d_out;
    __bf16* ws         = (__bf16*)d_ws;    // 16 KB

    basis_frags<<<dim3(1), dim3(256), 0, stream>>>(basis, ws);
    // 96 bc * 64 hb = 6144 WGs; wave wv covers wb in [16wv,16wv+16)
    dct_mfma<<<dim3(6144), dim3(256), 0, stream>>>(x, ws, out);
}

// Round 11
// 40.813 us; speedup vs baseline: 1.6703x; 1.0117x over previous
//
#include <hip/hip_runtime.h>

// LearnableDCT as GEMM on matrix cores (16x16x32 bf16 hi/lo, m89/m92-verified
// layouts) + LDS-transposed epilogue with full-line float4 stores.
//
// Round-9 post-mortem: write-amp fixed (kernel now faster than the 6.9 TB/s
// fill kernels; write floor ~14.5us, we're ~38us). Remaining cost: per-WG
// startup (A-frags re-read 6144x) and __syncthreads' implicit vmcnt(0) drain
// serializing nontemporal stores into the critical path (m97's barrier-drain).
// Round 10/11: (1) 4 tiles/WG - A-frags loaded once; (2) LDS-only barriers
// (lgkmcnt(0)+s_barrier, vmcnt never drained in-loop) so stores/loads stay
// in flight across tiles; (3) f32x4 epilogue stores (256B row per
// lane-quarter; __builtin_nontemporal_store needs a clang ext-vector type,
// NOT HIP's float4 struct — round-10 compile fail).

typedef float f32x4 __attribute__((ext_vector_type(4)));
typedef __bf16 bf16x8 __attribute__((ext_vector_type(8)));

static __device__ __forceinline__ f32x4 mfma16(bf16x8 a, bf16x8 b, f32x4 c) {
    return __builtin_amdgcn_mfma_f32_16x16x32_bf16(a, b, c, 0, 0, 0);
}

// Pre-kernel: basis -> per-lane hi/lo A-fragments in ws (verified round 8).
// ws layout: [F=((t*2+h)*2+p)][lane][8 bf16], 16 frags * 1KB = 16KB.
__global__ void basis_frags(const float* __restrict__ bsrc,
                            __bf16* __restrict__ ws)
{
    const int lane = threadIdx.x & 63;
    #pragma unroll
    for (int rr = 0; rr < 2; ++rr) {
        const int th = (threadIdx.x >> 6) + rr * 4;   // 0..7 : t=th>>1, h=th&1
        const int kk = ((th >> 1) << 4) + (lane & 15);
        const int nn = ((lane >> 4) << 3) + ((th & 1) << 5);
        const int Fh = th * 2, Fl = th * 2 + 1;
        #pragma unroll
        for (int j = 0; j < 8; ++j) {
            const float v = bsrc[kk * 64 + nn + j];
            const __bf16 h = (__bf16)v;
            ws[(Fh * 64 + lane) * 8 + j] = h;
            ws[(Fl * 64 + lane) * 8 + j] = (__bf16)(v - (float)h);
        }
    }
}

#define MAKE_BX(va, vb, XH, XL)                                        \
    {                                                                  \
        const float vv[8] = {va.x, va.y, va.z, va.w,                   \
                             vb.x, vb.y, vb.z, vb.w};                  \
        _Pragma("unroll")                                              \
        for (int j = 0; j < 8; ++j) {                                  \
            const __bf16 hh = (__bf16)vv[j];                           \
            XH[j] = hh;                                                \
            XL[j] = (__bf16)(vv[j] - (float)hh);                       \
        }                                                              \
    }

#define LSTRIDE 68   // dword stride: bank-rotating, conflict-free both phases
#define NT 4         // tiles (hb rows) per WG

__global__ __launch_bounds__(256) void dct_mfma(
    const float* __restrict__ x,
    const __bf16* __restrict__ wsf,
    float* __restrict__ out)
{
    __shared__ float lds[64 * LSTRIDE];   // 17.4 KB

    const int lane = threadIdx.x & 63;
    const int wv   = threadIdx.x >> 6;   // 0..3
    const int c15  = lane & 15;
    const int gq   = lane >> 4;          // 0..3
    const int wb0  = wv << 4;

    const int g0  = blockIdx.x * NT;     // NT consecutive hb, same bc
    const int bc  = g0 >> 6;
    const int hb0 = g0 & 63;

    // A fragments, loaded ONCE per WG (16KB ws, L1/L2-resident)
    bf16x8 A[16];
    const uint4* wp = reinterpret_cast<const uint4*>(wsf) + lane;
    #pragma unroll
    for (int F = 0; F < 16; ++F)
        A[F] = __builtin_bit_cast(bf16x8, wp[F * 64]);

    const float* xp0 = x + ((size_t)bc << 18) + ((size_t)hb0 << 12)
                         + ((wb0 + c15) << 3);
    float* ob = out + ((size_t)bc << 18) + (hb0 << 6) + (c15 << 2);

    #pragma unroll 1
    for (int t = 0; t < NT; ++t) {
        // ---- compute phase: x loads, cvt, MFMA, LDS writes ----
        const float* xp = xp0 + ((size_t)t << 12);
        const float4 a0 = *reinterpret_cast<const float4*>(xp + gq * 512);
        const float4 a1 = *reinterpret_cast<const float4*>(xp + gq * 512 + 4);
        const float4 b0 = *reinterpret_cast<const float4*>(xp + (gq + 4) * 512);
        const float4 b1 = *reinterpret_cast<const float4*>(xp + (gq + 4) * 512 + 4);

        bf16x8 Xh0, Xl0, Xh1, Xl1;
        MAKE_BX(a0, a1, Xh0, Xl0)
        MAKE_BX(b0, b1, Xh1, Xl1)

        #pragma unroll
        for (int tt = 0; tt < 4; ++tt) {
            f32x4 c = {0.f, 0.f, 0.f, 0.f};
            c = mfma16(A[(tt*2+0)*2+0], Xh0, c);   // bh*xh
            c = mfma16(A[(tt*2+0)*2+0], Xl0, c);   // bh*xl
            c = mfma16(A[(tt*2+0)*2+1], Xh0, c);   // bl*xh
            c = mfma16(A[(tt*2+1)*2+0], Xh1, c);
            c = mfma16(A[(tt*2+1)*2+0], Xl1, c);
            c = mfma16(A[(tt*2+1)*2+1], Xh1, c);

            const int kbase = (tt << 4) + (gq << 2);
            #pragma unroll
            for (int r = 0; r < 4; ++r)
                lds[(kbase + r) * LSTRIDE + wb0 + c15] = c[r];
        }

        // LDS-only barrier: drain DS ops, do NOT drain vmcnt (stores/loads
        // stay in flight across the barrier).
        asm volatile("s_waitcnt lgkmcnt(0)" ::: "memory");
        __builtin_amdgcn_s_barrier();

        // ---- epilogue: lane-quarter stores one full 256B k-row ----
        float* obt = ob + ((size_t)t << 6);
        #pragma unroll
        for (int kk = 0; kk < 4; ++kk) {
            const int k = (wv << 4) + (kk << 2) + gq;
            const f32x4 v = *reinterpret_cast<const f32x4*>(
                &lds[k * LSTRIDE + (c15 << 2)]);
            __builtin_nontemporal_store(
                v, reinterpret_cast<f32x4*>(obt + ((size_t)k << 12)));
        }

        // reads of tile t done before anyone writes tile t+1
        asm volatile("s_waitcnt lgkmcnt(0)" ::: "memory");
        __builtin_amdgcn_s_barrier();
    }
}

extern "C" void kernel_launch(void* const* d_in, const int* in_sizes, int n_in,
                              void* d_out, int out_size, void* d_ws, size_t ws_size,
                              hipStream_t stream) {
    const float* x     = (const float*)d_in[0];
    const float* basis = (const float*)d_in[1];
    float* out         = (float*)d_out;
    __bf16* ws         = (__bf16*)d_ws;    // 16 KB

    basis_frags<<<dim3(1), dim3(256), 0, stream>>>(basis, ws);
    // 6144 tiles / NT per WG = 1536 WGs
    dct_mfma<<<dim3(6144 / NT), dim3(256), 0, stream>>>(x, ws, out);
}